// Round 4
// baseline (114.734 us; speedup 1.0000x reference)
//
#include <hip/hip_runtime.h>
#include <hip/hip_bf16.h>

typedef __attribute__((ext_vector_type(8))) short bf16x8;
typedef __attribute__((ext_vector_type(4))) float f32x4;
typedef __attribute__((ext_vector_type(4))) unsigned int u32x4;
typedef __attribute__((ext_vector_type(2))) unsigned int u32x2;

__device__ __forceinline__ float b2f(unsigned short u) {
  unsigned int x = ((unsigned int)u) << 16;
  float f;
  __builtin_memcpy(&f, &x, 4);
  return f;
}
__device__ __forceinline__ unsigned short f2b(float f) {
  __hip_bfloat16 h = __float2bfloat16(f);
  unsigned short u;
  __builtin_memcpy(&u, &h, 2);
  return u;
}
__device__ __forceinline__ float ldE(const float* p) { return *p; }
__device__ __forceinline__ float ldE(const unsigned short* p) { return b2f(*p); }
__device__ __forceinline__ void stC(float* p, float v) { *p = v; }
__device__ __forceinline__ void stC(unsigned short* p, float v) { *p = f2b(v); }

// ---------------------------------------------------------------------------
// f32 [batch][R][C] -> bf16 [batch][C][R]  (64x64 tiles)
// ---------------------------------------------------------------------------
__global__ __launch_bounds__(256) void conv_transpose64(
    const float* __restrict__ src, unsigned short* __restrict__ dst,
    int R, int C) {
  __shared__ unsigned short tile[64][68];
  const int b = blockIdx.z;
  const float* s = src + (size_t)b * R * C;
  unsigned short* d = dst + (size_t)b * R * C;
  const int r0 = blockIdx.y * 64, c0 = blockIdx.x * 64;
  const int t = threadIdx.x;
#pragma unroll
  for (int p = 0; p < 4; ++p) {
    const int id = t + 256 * p;
    const int r = id >> 4, c4 = (id & 15) * 4;
    f32x4 v = *(const f32x4*)(s + (size_t)(r0 + r) * C + (c0 + c4));
#pragma unroll
    for (int j = 0; j < 4; ++j) tile[r][c4 + j] = f2b(v[j]);
  }
  __syncthreads();
#pragma unroll
  for (int p = 0; p < 2; ++p) {
    const int id = t + 256 * p;
    const int oc = id >> 3, cr8 = (id & 7) * 8;
    u32x4 v;
    unsigned short* pv = (unsigned short*)&v;
#pragma unroll
    for (int j = 0; j < 8; ++j) pv[j] = tile[cr8 + j][oc];
    *(u32x4*)(d + (size_t)(c0 + oc) * R + (r0 + cr8)) = v;
  }
}

// ---------------------------------------------------------------------------
// W' transpose: dst[o][f] = bf16( scale*W[f][o] + diag*(o==f) )
// ---------------------------------------------------------------------------
__global__ __launch_bounds__(256) void conv_transpose_wprime(
    const float* __restrict__ src, unsigned short* __restrict__ dst,
    float scale, float diag) {
  __shared__ float tile[64][65];
  const int r0 = blockIdx.y * 64, c0 = blockIdx.x * 64;
  const int t = threadIdx.x;
#pragma unroll
  for (int p = 0; p < 4; ++p) {
    const int id = t + 256 * p;
    const int r = id >> 4, c4 = (id & 15) * 4;
    f32x4 v = *(const f32x4*)(src + (size_t)(r0 + r) * 1024 + (c0 + c4));
#pragma unroll
    for (int j = 0; j < 4; ++j) tile[r][c4 + j] = v[j];
  }
  __syncthreads();
#pragma unroll
  for (int p = 0; p < 2; ++p) {
    const int id = t + 256 * p;
    const int oc = id >> 3, cr8 = (id & 7) * 8;
    u32x4 v;
    unsigned short* pv = (unsigned short*)&v;
#pragma unroll
    for (int j = 0; j < 8; ++j) {
      const int o = c0 + oc, f = r0 + cr8 + j;
      float val = scale * tile[cr8 + j][oc] + (o == f ? diag : 0.f);
      pv[j] = f2b(val);
    }
    *(u32x4*)(dst + (size_t)(c0 + oc) * 1024 + (r0 + cr8)) = v;
  }
}

// ---------------------------------------------------------------------------
// straight f32 -> bf16 convert (adj).
// ---------------------------------------------------------------------------
__global__ __launch_bounds__(256) void conv_bf16(const float* __restrict__ src,
                                                 unsigned short* __restrict__ dst,
                                                 int n) {
  const int i = (blockIdx.x * 256 + threadIdx.x) * 4;
  if (i >= n) return;
  f32x4 v = *(const f32x4*)(src + i);
  unsigned short o[4];
#pragma unroll
  for (int j = 0; j < 4; ++j) o[j] = f2b(v[j]);
  u32x2 pk;
  __builtin_memcpy(&pk, o, 8);
  *(u32x2*)(dst + i) = pk;
}

// ---------------------------------------------------------------------------
// 256x256-tile 8-phase GEMM on one big matrix product, K=1024.
// DECOMP=0: M=1024, N=16384 (A=adj shared; BT=XT; C/E batch-column mapped)
// DECOMP=1: M=16384, N=1024 (A=S flat; BT=W'; C flat)
// 1-D grid of 256 blocks, chunked XCD swizzle (T1): nid=(bid&7)*32+(bid>>3);
// within an XCD chunk, blocks share the A-panel -> L2-resident reuse.
// 512 thr = 8 waves (2M x 4N). LDS 128KB dbuf, XOR chunk swizzle (T2).
// Per K-tile: 4 phases {dsread | stage half | bar | lgkm0 | prio 16xMFMA | bar};
// counted vmcnt(4) once per K-tile (T4).
// ---------------------------------------------------------------------------
template <int DECOMP, typename ET, typename CT, bool HASE>
__global__ __launch_bounds__(512, 2) void gemm256(
    const unsigned short* __restrict__ A, const unsigned short* __restrict__ BT,
    const ET* __restrict__ E, CT* __restrict__ C, float c0, float c1) {
  constexpr int K = 1024;
  constexpr int NT = 16;  // K/64
  constexpr size_t NF = 1024ull * 1024ull;
  __shared__ unsigned short lds[4][16384];  // [buf*2+op][256*64]
  const int bid = blockIdx.x;
  const int nid = (bid & 7) * 32 + (bid >> 3);  // XCD chunk remap (bijective)
  int ty, tx;
  if (DECOMP == 0) { ty = nid >> 6; tx = nid & 63; }   // chunk: ty const
  else             { ty = nid >> 2; tx = nid & 3; }    // chunk: 8 ty x 4 tx
  const size_t m0 = (size_t)ty * 256, n0 = (size_t)tx * 256;

  const int t = threadIdx.x, lane = t & 63, wv = t >> 6;
  const int wm = (wv >> 2) * 128, wn = (wv & 3) * 64;

  f32x4 acc[8][4];
#pragma unroll
  for (int i = 0; i < 8; ++i)
#pragma unroll
    for (int j = 0; j < 4; ++j) acc[i][j] = (f32x4){0.f, 0.f, 0.f, 0.f};

  bf16x8 areg[4][2], b0r[2][2], b1r[2][2];

  auto STAGE = [&](int buf, int op, int half, const unsigned short* gbase,
                   size_t rowbase, int k0) {
#pragma unroll
    for (int l = 0; l < 2; ++l) {
      const int id = l * 512 + t;
      const int rl = id >> 3, c = id & 7;
      const int gc = (c ^ (rl & 7)) << 3;  // pre-swizzled global chunk
      const unsigned short* g =
          gbase + (rowbase + half * 128 + rl) * K + k0 + gc;
      unsigned short* dst =
          &lds[buf * 2 + op][half * 8192 + (l * 512 + wv * 64) * 8];
      __builtin_amdgcn_global_load_lds(
          (const __attribute__((address_space(1))) unsigned int*)g,
          (__attribute__((address_space(3))) unsigned int*)dst, 16, 0, 0);
    }
  };

#define LOAD_A(MH)                                                     \
  {                                                                    \
    const unsigned short* Ard = lds[rd * 2 + 0];                       \
    _Pragma("unroll") for (int mi = 0; mi < 4; ++mi)                   \
        _Pragma("unroll") for (int kk = 0; kk < 2; ++kk) {             \
      const int row = wm + (MH)*64 + mi * 16 + (lane & 15);            \
      const int ch = ((kk * 4 + (lane >> 4)) ^ (row & 7)) << 3;        \
      areg[mi][kk] = *(const bf16x8*)(Ard + row * 64 + ch);            \
    }                                                                  \
  }
#define LOAD_B(NH, BR)                                                 \
  {                                                                    \
    const unsigned short* Brd = lds[rd * 2 + 1];                       \
    _Pragma("unroll") for (int nj = 0; nj < 2; ++nj)                   \
        _Pragma("unroll") for (int kk = 0; kk < 2; ++kk) {             \
      const int row = wn + (NH)*32 + nj * 16 + (lane & 15);            \
      const int ch = ((kk * 4 + (lane >> 4)) ^ (row & 7)) << 3;        \
      BR[nj][kk] = *(const bf16x8*)(Brd + row * 64 + ch);              \
    }                                                                  \
  }
#define MFMA_Q(MH, NH, BR)                                             \
  do {                                                                 \
    __builtin_amdgcn_s_setprio(1);                                     \
    _Pragma("unroll") for (int mi = 0; mi < 4; ++mi)                   \
        _Pragma("unroll") for (int nj = 0; nj < 2; ++nj)               \
            _Pragma("unroll") for (int kk = 0; kk < 2; ++kk)           \
        acc[(MH)*4 + mi][(NH)*2 + nj] =                                \
        __builtin_amdgcn_mfma_f32_16x16x32_bf16(                       \
            areg[mi][kk], BR[nj][kk], acc[(MH)*4 + mi][(NH)*2 + nj],   \
            0, 0, 0);                                                  \
    __builtin_amdgcn_s_setprio(0);                                     \
  } while (0)
#define LGKM0                                          \
  asm volatile("s_waitcnt lgkmcnt(0)" ::: "memory");   \
  __builtin_amdgcn_sched_barrier(0)

  // prologue: tile0 fully + tile1 {B0, A0}; leave 4 loads in flight
  STAGE(0, 0, 0, A, m0, 0);
  STAGE(0, 0, 1, A, m0, 0);
  STAGE(0, 1, 0, BT, n0, 0);
  STAGE(0, 1, 1, BT, n0, 0);
  STAGE(1, 1, 0, BT, n0, 64);
  STAGE(1, 0, 0, A, m0, 64);
  asm volatile("s_waitcnt vmcnt(4)" ::: "memory");
  __builtin_amdgcn_s_barrier();

  for (int tt = 0; tt < NT; ++tt) {
    const int rd = tt & 1;
    // ---- phase 1: quadrant (m0,n0) ----
    LOAD_A(0);
    LOAD_B(0, b0r);
    if (tt + 1 < NT) STAGE((tt + 1) & 1, 1, 1, BT, n0, (tt + 1) * 64);
    __builtin_amdgcn_s_barrier();
    LGKM0;
    MFMA_Q(0, 0, b0r);
    __builtin_amdgcn_s_barrier();
    // ---- phase 2: quadrant (m0,n1) ----
    LOAD_B(1, b1r);
    if (tt + 1 < NT) STAGE((tt + 1) & 1, 0, 1, A, m0, (tt + 1) * 64);
    __builtin_amdgcn_s_barrier();
    LGKM0;
    MFMA_Q(0, 1, b1r);
    __builtin_amdgcn_s_barrier();
    // ---- phase 3: quadrant (m1,n1) ----
    LOAD_A(1);
    if (tt + 2 < NT) STAGE(rd, 1, 0, BT, n0, (tt + 2) * 64);
    __builtin_amdgcn_s_barrier();
    LGKM0;
    MFMA_Q(1, 1, b1r);
    __builtin_amdgcn_s_barrier();
    // ---- phase 4: quadrant (m1,n0) ----
    if (tt + 2 < NT) STAGE(rd, 0, 0, A, m0, (tt + 2) * 64);
    __builtin_amdgcn_s_barrier();
    LGKM0;
    MFMA_Q(1, 0, b0r);
    asm volatile("s_waitcnt vmcnt(4)" ::: "memory");
    __builtin_amdgcn_s_barrier();
  }

  // epilogue: addr = base + lrow*1024 + lcol
  size_t base;
  if (DECOMP == 0)
    base = (n0 >> 10) * NF + (n0 & 1023) + m0 * 1024;  // batch-column mapping
  else
    base = m0 * 1024 + n0;  // flat
  const ET* Eb = E + base;
  CT* Cb = C + base;
#pragma unroll
  for (int mi = 0; mi < 8; ++mi) {
#pragma unroll
    for (int r = 0; r < 4; ++r) {
      const int lrow = wm + mi * 16 + (lane >> 4) * 4 + r;
#pragma unroll
      for (int nj = 0; nj < 4; ++nj) {
        const int lcol = wn + nj * 16 + (lane & 15);
        float v = c0 * acc[mi][nj][r];
        if (HASE) v += c1 * ldE(Eb + (size_t)lrow * 1024 + lcol);
        stC(Cb + (size_t)lrow * 1024 + lcol, v);
      }
    }
  }
#undef LOAD_A
#undef LOAD_B
#undef MFMA_Q
#undef LGKM0
}

// ---------------------------------------------------------------------------
// out = support·(theta*W + (1-theta)*I), support = 0.9*(adj·X_b) + 0.1*h0
// theta = log(1.5) (static: lamda=0.5, l=1 in setup_inputs)
// ---------------------------------------------------------------------------
extern "C" void kernel_launch(void* const* d_in, const int* in_sizes, int n_in,
                              void* d_out, int out_size, void* d_ws,
                              size_t ws_size, hipStream_t stream) {
  const float* X = (const float*)d_in[0];    // [16,1024,1024] f32
  const float* adj = (const float*)d_in[1];  // [1024,1024] f32
  const float* h0 = (const float*)d_in[2];   // [16,1024,1024] f32
  const float* W = (const float*)d_in[3];    // [1024,1024] f32
  float* out = (float*)d_out;                // [16,1024,1024] f32

  const size_t NF = 1024ull * 1024ull;
  unsigned short* XT = (unsigned short*)d_ws;  // 16*NF bf16: XT[b][f][n]
  unsigned short* WT = XT + 16 * NF;           // NF bf16: theta*W^T+(1-theta)I
  unsigned short* AJ = WT + NF;                // NF bf16
  unsigned short* S = AJ + NF;                 // 16*NF bf16, flat [16384][1024]

  const float theta = 0.405465108f;  // log(1.5)
  const float alpha = 0.1f;

  conv_transpose64<<<dim3(16, 16, 16), 256, 0, stream>>>(X, XT, 1024, 1024);
  conv_transpose_wprime<<<dim3(16, 16, 1), 256, 0, stream>>>(
      W, WT, theta, 1.0f - theta);
  conv_bf16<<<dim3(1024), 256, 0, stream>>>(adj, AJ, 1024 * 1024);

  // GEMM1 (one big product): S[:, b*1024+f... ] via batch-column mapping
  // S = bf16( 0.9*(adj · X') + 0.1*h0 ),  X'[m, b*1024+f] = X[b,m,f]
  gemm256<0, float, unsigned short, true>
      <<<dim3(256), 512, 0, stream>>>(AJ, XT, h0, S, 1.0f - alpha, alpha);
  // GEMM2: out = f32( S · W'^T ),  S flat [16384][1024]
  gemm256<1, unsigned short, float, false>
      <<<dim3(256), 512, 0, stream>>>(S, WT, (const unsigned short*)S, out,
                                      1.0f, 0.0f);
}